// Round 3
// baseline (2017.126 us; speedup 1.0000x reference)
//
#include <hip/hip_runtime.h>
#include <stdint.h>

typedef __attribute__((ext_vector_type(8))) short bf16x8;
typedef __attribute__((ext_vector_type(4))) float f32x4;

#define N_NODES 8192
#define E_EDGES 163840
#define NGRAPH  32

#define INV_SQRT30 0.18257419f
#define SH0C       0.22360680f   /* 1/sqrt(20) */
#define SQRT3C     1.73205081f
#define INV_SQRT3  0.57735027f
#define INV_SQRT10 0.31622777f
#define SQ2C       0.70710678f

// ---------------- workspace layout (bytes) ----------------
enum : unsigned {
  OFF_W1P1 = 0u,       OFF_W2P1 = 65536u,   OFF_W3P1 = 589824u,  OFF_W4P1 = 655360u,
  OFF_W1P2 = 851968u,  OFF_W2P2 = 917504u,  OFF_W3P2 = 1441792u, OFF_W4P2 = 1507328u,
  OFF_B1P1 = 1515520u, OFF_B2P1 = 1517568u, OFF_B3P1 = 1519616u, OFF_B4P1 = 1519872u,
  OFF_B1P2 = 1526016u, OFF_B2P2 = 1528064u, OFF_B3P2 = 1530112u, OFF_B4P2 = 1530368u,
  OFF_HN   = 1530624u, // [8192][32] f32  (emb[z]/sqrt(30))
  OFF_H2   = 2579200u, // [8192][64] f32
  OFF_AGG  = 4676352u, // [8192][70] f32
  OFF_AGG2 = 6970112u, // [8192] f32
  OFF_GSUM = 7002880u, // [32] f32
  OFF_END  = 7003008u
};

__device__ __forceinline__ uint16_t f2bf(float f){
  union { float f; uint32_t u; } v; v.f = f;
  uint32_t r = v.u + 0x7fffu + ((v.u >> 16) & 1u);
  return (uint16_t)(r >> 16);
}
__device__ __forceinline__ float swishf(float x){ return x / (1.f + __expf(-x)); }

// ---------------- weight pre-pack (f32 src -> bf16 MFMA B-fragment order) ----------------
// packed index = ((kk*NT + nn)*64 + lane)*8 + b  ->  W[kk*32 + (lane>>4)*8 + b][nn*16 + (lane&15)]
__device__ __forceinline__ void pack_mat(const float* __restrict__ src, int K, int N, int NP,
                                         uint16_t* __restrict__ dst, int t)
{
  int lane = t & 63;
  int tile = t >> 6;
  int NT = NP >> 4;
  int nn = tile % NT, kk = tile / NT;
  int k0 = kk*32 + ((lane >> 4) << 3);
  int n  = nn*16 + (lane & 15);
  union { short s[8]; bf16x8 v; } tmp;
#pragma unroll
  for (int b = 0; b < 8; ++b) {
    int k = k0 + b;
    tmp.s[b] = (k < K && n < N) ? (short)f2bf(src[(size_t)k*N + n]) : (short)0;
  }
  *reinterpret_cast<bf16x8*>(dst + (size_t)t*8) = tmp.v;
}

__global__ void prep_kernel(const float* w1a, const float* w2a, const float* w3a, const float* w4a,
                            const float* w1b, const float* w2b, const float* w3b, const float* w4b,
                            const float* b1a, const float* b2a, const float* b3a, const float* b4a,
                            const float* b1b, const float* b2b, const float* b3b, const float* b4b,
                            const float* emb, const int* z, char* ws)
{
  int t = blockIdx.x * 256 + threadIdx.x;
  if      (t < 4096)   pack_mat(w1a, 40, 500, 512,  (uint16_t*)(ws + OFF_W1P1), t);
  else if (t < 36864)  pack_mat(w2a, 500,500, 512,  (uint16_t*)(ws + OFF_W2P1), t - 4096);
  else if (t < 40960)  pack_mat(w3a, 500, 50, 64,   (uint16_t*)(ws + OFF_W3P1), t - 36864);
  else if (t < 53248)  pack_mat(w4a, 50,1500, 1536, (uint16_t*)(ws + OFF_W4P1), t - 40960);
  else if (t < 57344)  pack_mat(w1b, 40, 500, 512,  (uint16_t*)(ws + OFF_W1P2), t - 53248);
  else if (t < 90112)  pack_mat(w2b, 500,500, 512,  (uint16_t*)(ws + OFF_W2P2), t - 57344);
  else if (t < 94208)  pack_mat(w3b, 500, 50, 64,   (uint16_t*)(ws + OFF_W3P2), t - 90112);
  else if (t < 94720)  pack_mat(w4b, 50,  40, 64,   (uint16_t*)(ws + OFF_W4P2), t - 94208);
  else if (t < 98496) {
    int loc = t - 94720;
    const float* src; float* dst; int realN;
    if      (loc < 512)  { src=b1a; dst=(float*)(ws+OFF_B1P1); realN=500; }
    else if (loc < 1024) { src=b2a; dst=(float*)(ws+OFF_B2P1); realN=500;  loc -= 512;  }
    else if (loc < 1088) { src=b3a; dst=(float*)(ws+OFF_B3P1); realN=50;   loc -= 1024; }
    else if (loc < 2624) { src=b4a; dst=(float*)(ws+OFF_B4P1); realN=1500; loc -= 1088; }
    else if (loc < 3136) { src=b1b; dst=(float*)(ws+OFF_B1P2); realN=500;  loc -= 2624; }
    else if (loc < 3648) { src=b2b; dst=(float*)(ws+OFF_B2P2); realN=500;  loc -= 3136; }
    else if (loc < 3712) { src=b3b; dst=(float*)(ws+OFF_B3P2); realN=50;   loc -= 3648; }
    else                 { src=b4b; dst=(float*)(ws+OFF_B4P2); realN=40;   loc -= 3712; }
    dst[loc] = (loc < realN) ? src[loc] : 0.f;
  }
  else if (t < 360640) {
    int i = t - 98496;
    int n = i >> 5, u = i & 31;
    float v = 0.f;
    if (u < 30) v = emb[(size_t)z[n]*30 + u] * INV_SQRT30;
    ((float*)(ws + OFF_HN))[i] = v;
  }
}

// ---------------- fused GEMM stage (per-wave: 4 rowblocks x NTW ntiles) ----------------
template<int KP, int NTW>
__device__ __forceinline__ void gemm_stage(const uint16_t* inb, uint16_t* outb,
                                           const uint16_t* __restrict__ Bp, const float* __restrict__ bp,
                                           int NTtot, int ntbase, int lane, bool do_swish, int outPitchB)
{
  const int r = lane & 15, q = lane >> 4;
  f32x4 zv = {0.f, 0.f, 0.f, 0.f};
  f32x4 acc[4][NTW];
#pragma unroll
  for (int a = 0; a < 4; ++a)
#pragma unroll
    for (int b = 0; b < NTW; ++b) acc[a][b] = zv;

#pragma unroll
  for (int kk = 0; kk < KP/32; ++kk) {
    bf16x8 afrag[4];
#pragma unroll
    for (int rb = 0; rb < 4; ++rb) {
      int row = rb*16 + r;
      int byte = (row*KP + kk*32 + q*8) * 2; byte ^= ((row & 7) << 4);
      afrag[rb] = *reinterpret_cast<const bf16x8*>((const char*)inb + byte);
    }
#pragma unroll
    for (int nt = 0; nt < NTW; ++nt) {
      bf16x8 bfrag = *reinterpret_cast<const bf16x8*>(Bp + ((size_t)(kk*NTtot + ntbase + nt)*64 + lane)*8);
#pragma unroll
      for (int rb = 0; rb < 4; ++rb)
        acc[rb][nt] = __builtin_amdgcn_mfma_f32_16x16x32_bf16(afrag[rb], bfrag, acc[rb][nt], 0, 0, 0);
    }
  }
#pragma unroll
  for (int nt = 0; nt < NTW; ++nt) {
    int col = (ntbase + nt)*16 + r;
    float bias = bp[col];
#pragma unroll
    for (int rb = 0; rb < 4; ++rb)
#pragma unroll
      for (int i = 0; i < 4; ++i) {
        int row = rb*16 + q*4 + i;
        float v = acc[rb][nt][i] + bias;
        if (do_swish) v = swishf(v);
        int byte = row*outPitchB + col*2; byte ^= ((row & 7) << 4);
        *(uint16_t*)((char*)outb + byte) = f2bf(v);
      }
  }
}

// ---------------- edge megakernel ----------------
template<int LAYER>
__global__ __launch_bounds__(512, 2)
void edge_kernel(const float* __restrict__ pos, const int* __restrict__ eidx,
                 const char* __restrict__ ws, float* __restrict__ aggout,
                 const float* __restrict__ hsrc)
{
  __shared__ __align__(16) uint16_t actA[64*512];
  __shared__ __align__(16) uint16_t actB[64*512];
  __shared__ float mbuf[64*50];   // L1: m0(40)+m1raw(10) per edge. L2: [0..63]=medge, [64..703]=D
  __shared__ float xjb[64*60];    // L1: pitch 30 (hN gather). L2: pitch 60 (h2 gather)
  __shared__ float shl[64*3];     // sqrt(3)*unit/sqrt(20)
  __shared__ float rbuf[64];
  __shared__ int   rowl[64];
  __shared__ int   coll[64];

  const uint16_t* W1p = (const uint16_t*)(ws + (LAYER==1 ? OFF_W1P1 : OFF_W1P2));
  const uint16_t* W2p = (const uint16_t*)(ws + (LAYER==1 ? OFF_W2P1 : OFF_W2P2));
  const uint16_t* W3p = (const uint16_t*)(ws + (LAYER==1 ? OFF_W3P1 : OFF_W3P2));
  const uint16_t* W4p = (const uint16_t*)(ws + (LAYER==1 ? OFF_W4P1 : OFF_W4P2));
  const float* b1p = (const float*)(ws + (LAYER==1 ? OFF_B1P1 : OFF_B1P2));
  const float* b2p = (const float*)(ws + (LAYER==1 ? OFF_B2P1 : OFF_B2P2));
  const float* b3p = (const float*)(ws + (LAYER==1 ? OFF_B3P1 : OFF_B3P2));
  const float* b4p = (const float*)(ws + (LAYER==1 ? OFF_B4P1 : OFF_B4P2));

  const int tid  = threadIdx.x;
  const int lane = tid & 63;
  const int wv   = tid >> 6;
  const int e0   = blockIdx.x * 64;

  // stage 0: edge meta
  if (tid < 64) {
    int e = e0 + tid;
    int rn = eidx[e];
    int cn = eidx[E_EDGES + e];
    rowl[tid] = rn; coll[tid] = cn;
    float ax = pos[rn*3+0] - pos[cn*3+0];
    float ay = pos[rn*3+1] - pos[cn*3+1];
    float az = pos[rn*3+2] - pos[cn*3+2];
    float rr = sqrtf(ax*ax + ay*ay + az*az + 1e-12f);
    rbuf[tid] = rr;
    float s = SQRT3C * SH0C / rr;
    shl[tid*3+0] = ax*s; shl[tid*3+1] = ay*s; shl[tid*3+2] = az*s;
  }
  __syncthreads();

  // stage 0b: basis into actB (pitch 64 elems), xj gather, zero message buffers
  for (int i = tid; i < 64*64; i += 512) {
    int e = i >> 6, c = i & 63;
    float v = 0.f;
    if (c < 40) { float t = rbuf[e]*3.9f - (float)c; v = __expf(-t*t); }
    int byte = (e*64 + c)*2; byte ^= ((e & 7) << 4);
    *(uint16_t*)((char*)actB + byte) = f2bf(v);
  }
  if (LAYER == 1) {
    for (int i = tid; i < 64*30; i += 512) {
      int e = i/30, u = i - e*30;
      xjb[i] = hsrc[(size_t)rowl[e]*32 + u];
    }
    for (int i = tid; i < 64*50; i += 512) mbuf[i] = 0.f;
  } else {
    for (int i = tid; i < 64*60; i += 512) {
      int e = i/60, u = i - e*60;
      xjb[i] = hsrc[(size_t)rowl[e]*64 + u];
    }
    if (tid < 64) mbuf[tid] = 0.f;
  }
  __syncthreads();

  if (LAYER == 2) {
    // D[e][v] = sum_m xj2[e,30+v*3+m]*sh[m]/sqrt(3)  -> mbuf[64 + e*10 + v]
    for (int i = tid; i < 640; i += 512) {
      int e = i/10, v = i - e*10;
      float d = 0.f;
#pragma unroll
      for (int m = 0; m < 3; ++m) d += xjb[e*60 + 30 + v*3 + m] * shl[e*3 + m];
      mbuf[64 + i] = d * INV_SQRT3;
    }
  }

  // GEMM1: basis(actB, pitch 64) -> act1(actA, pitch 512), swish
  gemm_stage<64, 4>(actB, actA, W1p, b1p, 32, wv*4, lane, true, 1024);
  __syncthreads();
  // GEMM2: act1(actA) -> act2(actB), swish
  gemm_stage<512, 4>(actA, actB, W2p, b2p, 32, wv*4, lane, true, 1024);
  __syncthreads();
  // GEMM3: act2(actB) -> x3(actA, pitch 64), swish  (waves 0..3 only)
  if (wv < 4)
    gemm_stage<512, 1>(actB, actA, W3p, b3p, 4, wv, lane, true, 128);
  __syncthreads();

  // GEMM4 + in-register consumption
  const int r_ = lane & 15, q_ = lane >> 4;
  f32x4 zv = {0.f, 0.f, 0.f, 0.f};
  if (LAYER == 1) {
#pragma unroll
    for (int ch = 0; ch < 3; ++ch) {
      f32x4 acc[4][4];
#pragma unroll
      for (int a = 0; a < 4; ++a)
#pragma unroll
        for (int b = 0; b < 4; ++b) acc[a][b] = zv;
#pragma unroll
      for (int kk = 0; kk < 2; ++kk) {
        bf16x8 afrag[4];
#pragma unroll
        for (int rb = 0; rb < 4; ++rb) {
          int row = rb*16 + r_;
          int byte = (row*64 + kk*32 + q_*8)*2; byte ^= ((row & 7) << 4);
          afrag[rb] = *reinterpret_cast<const bf16x8*>((const char*)actA + byte);
        }
#pragma unroll
        for (int nt = 0; nt < 4; ++nt) {
          int ntg = wv*12 + ch*4 + nt;
          bf16x8 bfrag = *reinterpret_cast<const bf16x8*>(W4p + ((size_t)(kk*96 + ntg)*64 + lane)*8);
#pragma unroll
          for (int rb = 0; rb < 4; ++rb)
            acc[rb][nt] = __builtin_amdgcn_mfma_f32_16x16x32_bf16(afrag[rb], bfrag, acc[rb][nt], 0, 0, 0);
        }
      }
#pragma unroll
      for (int nt = 0; nt < 4; ++nt) {
        int cg = (wv*12 + ch*4 + nt)*16 + r_;
        if (cg < 1500) {
          float bias = b4p[cg];
          int u, vd;
          if (cg < 1200) { u = cg/40; vd = cg - u*40; }
          else { int cc = cg - 1200; u = cc/10; vd = 40 + (cc - u*10); }
#pragma unroll
          for (int rb = 0; rb < 4; ++rb)
#pragma unroll
            for (int i2 = 0; i2 < 4; ++i2) {
              int e = rb*16 + q_*4 + i2;
              float w = acc[rb][nt][i2] + bias;
              atomicAdd(&mbuf[e*50 + vd], xjb[e*30 + u] * w);
            }
        }
      }
    }
  } else {
    if (wv < 4) {
      f32x4 acc[4];
#pragma unroll
      for (int a = 0; a < 4; ++a) acc[a] = zv;
#pragma unroll
      for (int kk = 0; kk < 2; ++kk) {
        bf16x8 afrag[4];
#pragma unroll
        for (int rb = 0; rb < 4; ++rb) {
          int row = rb*16 + r_;
          int byte = (row*64 + kk*32 + q_*8)*2; byte ^= ((row & 7) << 4);
          afrag[rb] = *reinterpret_cast<const bf16x8*>((const char*)actA + byte);
        }
        bf16x8 bfrag = *reinterpret_cast<const bf16x8*>(W4p + ((size_t)(kk*4 + wv)*64 + lane)*8);
#pragma unroll
        for (int rb = 0; rb < 4; ++rb)
          acc[rb] = __builtin_amdgcn_mfma_f32_16x16x32_bf16(afrag[rb], bfrag, acc[rb], 0, 0, 0);
      }
      int cg = wv*16 + r_;
      if (cg < 40) {
        float bias = b4p[cg];
#pragma unroll
        for (int rb = 0; rb < 4; ++rb)
#pragma unroll
          for (int i2 = 0; i2 < 4; ++i2) {
            int e = rb*16 + q_*4 + i2;
            float w = acc[rb][i2] + bias;
            float contrib = (cg < 30) ? xjb[e*60 + cg] * w * (SH0C * INV_SQRT30)
                                      : mbuf[64 + e*10 + (cg - 30)] * w * INV_SQRT10;
            atomicAdd(&mbuf[e], contrib);
          }
      }
    }
  }
  __syncthreads();

  // scatter to aggregation buffers
  if (LAYER == 1) {
    for (int i = tid; i < 64*70; i += 512) {
      int e = i/70, c = i - e*70;
      float v;
      if (c < 40) v = mbuf[e*50 + c] * SH0C;
      else { int vv = (c - 40)/3, k = (c - 40) - vv*3; v = mbuf[e*50 + 40 + vv] * shl[e*3 + k]; }
      atomicAdd(&aggout[(size_t)coll[e]*70 + c], v);
    }
  } else {
    if (tid < 64) atomicAdd(&aggout[coll[tid]], mbuf[tid]);
  }
}

// ---------------- node kernels ----------------
__global__ void node_mid(char* ws, const float* __restrict__ si1w)
{
  int nid = blockIdx.x * blockDim.x + threadIdx.x;
  if (nid >= N_NODES) return;
  const float* hN  = (const float*)(ws + OFF_HN)  + (size_t)nid*32;
  const float* agg = (const float*)(ws + OFF_AGG) + (size_t)nid*70;
  float* h2        = (float*)(ws + OFF_H2)        + (size_t)nid*64;

  float hn[30];
#pragma unroll
  for (int u = 0; u < 30; ++u) hn[u] = hN[u];   // already /sqrt(30)

  float h1[70];
#pragma unroll
  for (int v = 0; v < 40; ++v) {
    float s = 0.f;
#pragma unroll
    for (int u = 0; u < 30; ++u) s += hn[u] * si1w[u*40 + v];
    h1[v] = SQ2C * (s + agg[v]);
  }
#pragma unroll
  for (int c = 40; c < 70; ++c) h1[c] = agg[c];

#pragma unroll
  for (int u = 0; u < 30; ++u) h2[u] = swishf(h1[u]);
#pragma unroll
  for (int v = 0; v < 10; ++v) {
    float g = 1.f / (1.f + __expf(-h1[30 + v]));
#pragma unroll
    for (int k = 0; k < 3; ++k) h2[30 + v*3 + k] = h1[40 + v*3 + k] * g;
  }
}

__global__ void node_final(char* ws, const float* __restrict__ si2w, const int* __restrict__ batch)
{
  __shared__ float ls[NGRAPH];
  if (threadIdx.x < NGRAPH) ls[threadIdx.x] = 0.f;
  __syncthreads();
  int nid = blockIdx.x * blockDim.x + threadIdx.x;
  if (nid < N_NODES) {
    const float* h2   = (const float*)(ws + OFF_H2) + (size_t)nid*64;
    const float* agg2 = (const float*)(ws + OFF_AGG2);
    float s2 = 0.f;
#pragma unroll
    for (int u = 0; u < 30; ++u) s2 += h2[u] * si2w[u];
    float val = SQ2C * (s2 * INV_SQRT30 + agg2[nid]);
    atomicAdd(&ls[batch[nid]], val);
  }
  __syncthreads();
  if (threadIdx.x < NGRAPH)
    atomicAdd(((float*)(ws + OFF_GSUM)) + threadIdx.x, ls[threadIdx.x]);
}

__global__ void write_out(const char* ws, float* out)
{
  int g = threadIdx.x;
  if (g < NGRAPH) out[g] = ((const float*)(ws + OFF_GSUM))[g];
}

// ---------------- launch ----------------
extern "C" void kernel_launch(void* const* d_in, const int* in_sizes, int n_in,
                              void* d_out, int out_size, void* d_ws, size_t ws_size,
                              hipStream_t stream)
{
  const float* pos  = (const float*)d_in[0];
  const float* emb  = (const float*)d_in[1];
  const float* si1w = (const float*)d_in[2];
  const float* si2w = (const float*)d_in[3];
  const float* w1a = (const float*)d_in[4];  const float* b1a = (const float*)d_in[5];
  const float* w2a = (const float*)d_in[6];  const float* b2a = (const float*)d_in[7];
  const float* w3a = (const float*)d_in[8];  const float* b3a = (const float*)d_in[9];
  const float* w4a = (const float*)d_in[10]; const float* b4a = (const float*)d_in[11];
  const float* w1b = (const float*)d_in[12]; const float* b1b = (const float*)d_in[13];
  const float* w2b = (const float*)d_in[14]; const float* b2b = (const float*)d_in[15];
  const float* w3b = (const float*)d_in[16]; const float* b3b = (const float*)d_in[17];
  const float* w4b = (const float*)d_in[18]; const float* b4b = (const float*)d_in[19];
  const int* z     = (const int*)d_in[20];
  const int* eidx  = (const int*)d_in[21];
  const int* batch = (const int*)d_in[22];
  char* ws = (char*)d_ws;

  // zero accumulation buffers (agg, agg2, gsum are contiguous)
  hipMemsetAsync(ws + OFF_AGG, 0, OFF_END - OFF_AGG, stream);

  prep_kernel<<<1409, 256, 0, stream>>>(w1a, w2a, w3a, w4a, w1b, w2b, w3b, w4b,
                                        b1a, b2a, b3a, b4a, b1b, b2b, b3b, b4b,
                                        emb, z, ws);

  edge_kernel<1><<<E_EDGES/64, 512, 0, stream>>>(pos, eidx, ws,
                                                 (float*)(ws + OFF_AGG),
                                                 (const float*)(ws + OFF_HN));

  node_mid<<<N_NODES/256, 256, 0, stream>>>(ws, si1w);

  edge_kernel<2><<<E_EDGES/64, 512, 0, stream>>>(pos, eidx, ws,
                                                 (float*)(ws + OFF_AGG2),
                                                 (const float*)(ws + OFF_H2));

  node_final<<<N_NODES/256, 256, 0, stream>>>(ws, si2w, batch);

  write_out<<<1, 64, 0, stream>>>(ws, (float*)d_out);
}

// Round 4
// 1736.216 us; speedup vs baseline: 1.1618x; 1.1618x over previous
//
#include <hip/hip_runtime.h>
#include <stdint.h>

typedef __attribute__((ext_vector_type(8))) short bf16x8;
typedef __attribute__((ext_vector_type(4))) float f32x4;

#define N_NODES 8192
#define E_EDGES 163840
#define NGRAPH  32
#define MT      32          /* edges per block */

#define INV_SQRT30 0.18257419f
#define SH0C       0.22360680f   /* 1/sqrt(20) */
#define SQRT3C     1.73205081f
#define INV_SQRT3  0.57735027f
#define INV_SQRT10 0.31622777f
#define SQ2C       0.70710678f

// ---------------- workspace layout (bytes) ----------------
enum : unsigned {
  OFF_W1P1 = 0u,       OFF_W2P1 = 65536u,   OFF_W3P1 = 589824u,  OFF_W4P1 = 655360u,
  OFF_W1P2 = 851968u,  OFF_W2P2 = 917504u,  OFF_W3P2 = 1441792u, OFF_W4P2 = 1507328u,
  OFF_B1P1 = 1515520u, OFF_B2P1 = 1517568u, OFF_B3P1 = 1519616u, OFF_B4P1 = 1519872u,
  OFF_B1P2 = 1526016u, OFF_B2P2 = 1528064u, OFF_B3P2 = 1530112u, OFF_B4P2 = 1530368u,
  OFF_HN   = 1530624u, // [8192][32] f32  (emb[z]/sqrt(30))
  OFF_H2   = 2579200u, // [8192][64] f32
  OFF_AGG  = 4676352u, // [8192][70] f32
  OFF_AGG2 = 6970112u, // [8192] f32
  OFF_GSUM = 7002880u, // [32] f32
  OFF_END  = 7003008u
};

__device__ __forceinline__ uint16_t f2bf(float f){
  union { float f; uint32_t u; } v; v.f = f;
  uint32_t r = v.u + 0x7fffu + ((v.u >> 16) & 1u);
  return (uint16_t)(r >> 16);
}
__device__ __forceinline__ float swishf(float x){ return x / (1.f + __expf(-x)); }

// ---------------- weight pre-pack (f32 src -> bf16 MFMA B-fragment order) ----------------
// packed index = ((kk*NT + nn)*64 + lane)*8 + b  ->  W[kk*32 + (lane>>4)*8 + b][nn*16 + (lane&15)]
__device__ __forceinline__ void pack_mat(const float* __restrict__ src, int K, int N, int NP,
                                         uint16_t* __restrict__ dst, int t)
{
  int lane = t & 63;
  int tile = t >> 6;
  int NT = NP >> 4;
  int nn = tile % NT, kk = tile / NT;
  int k0 = kk*32 + ((lane >> 4) << 3);
  int n  = nn*16 + (lane & 15);
  union { short s[8]; bf16x8 v; } tmp;
#pragma unroll
  for (int b = 0; b < 8; ++b) {
    int k = k0 + b;
    tmp.s[b] = (k < K && n < N) ? (short)f2bf(src[(size_t)k*N + n]) : (short)0;
  }
  *reinterpret_cast<bf16x8*>(dst + (size_t)t*8) = tmp.v;
}

__global__ void prep_kernel(const float* w1a, const float* w2a, const float* w3a, const float* w4a,
                            const float* w1b, const float* w2b, const float* w3b, const float* w4b,
                            const float* b1a, const float* b2a, const float* b3a, const float* b4a,
                            const float* b1b, const float* b2b, const float* b3b, const float* b4b,
                            const float* emb, const int* z, char* ws)
{
  int t = blockIdx.x * 256 + threadIdx.x;
  if      (t < 4096)   pack_mat(w1a, 40, 500, 512,  (uint16_t*)(ws + OFF_W1P1), t);
  else if (t < 36864)  pack_mat(w2a, 500,500, 512,  (uint16_t*)(ws + OFF_W2P1), t - 4096);
  else if (t < 40960)  pack_mat(w3a, 500, 50, 64,   (uint16_t*)(ws + OFF_W3P1), t - 36864);
  else if (t < 53248)  pack_mat(w4a, 50,1500, 1536, (uint16_t*)(ws + OFF_W4P1), t - 40960);
  else if (t < 57344)  pack_mat(w1b, 40, 500, 512,  (uint16_t*)(ws + OFF_W1P2), t - 53248);
  else if (t < 90112)  pack_mat(w2b, 500,500, 512,  (uint16_t*)(ws + OFF_W2P2), t - 57344);
  else if (t < 94208)  pack_mat(w3b, 500, 50, 64,   (uint16_t*)(ws + OFF_W3P2), t - 90112);
  else if (t < 94720)  pack_mat(w4b, 50,  40, 64,   (uint16_t*)(ws + OFF_W4P2), t - 94208);
  else if (t < 98496) {
    int loc = t - 94720;
    const float* src; float* dst; int realN;
    if      (loc < 512)  { src=b1a; dst=(float*)(ws+OFF_B1P1); realN=500; }
    else if (loc < 1024) { src=b2a; dst=(float*)(ws+OFF_B2P1); realN=500;  loc -= 512;  }
    else if (loc < 1088) { src=b3a; dst=(float*)(ws+OFF_B3P1); realN=50;   loc -= 1024; }
    else if (loc < 2624) { src=b4a; dst=(float*)(ws+OFF_B4P1); realN=1500; loc -= 1088; }
    else if (loc < 3136) { src=b1b; dst=(float*)(ws+OFF_B1P2); realN=500;  loc -= 2624; }
    else if (loc < 3648) { src=b2b; dst=(float*)(ws+OFF_B2P2); realN=500;  loc -= 3136; }
    else if (loc < 3712) { src=b3b; dst=(float*)(ws+OFF_B3P2); realN=50;   loc -= 3648; }
    else                 { src=b4b; dst=(float*)(ws+OFF_B4P2); realN=40;   loc -= 3712; }
    dst[loc] = (loc < realN) ? src[loc] : 0.f;
  }
  else if (t < 360640) {
    int i = t - 98496;
    int n = i >> 5, u = i & 31;
    float v = 0.f;
    if (u < 30) v = emb[(size_t)z[n]*30 + u] * INV_SQRT30;
    ((float*)(ws + OFF_HN))[i] = v;
  }
}

// ---------------- fused GEMM stage (per-wave: 2 rowblocks x NTW ntiles) ----------------
template<int KP, int NTW>
__device__ __forceinline__ void gemm_stage(const uint16_t* inb, uint16_t* outb,
                                           const uint16_t* __restrict__ Bp, const float* __restrict__ bp,
                                           int NTtot, int ntbase, int lane, int outPitchB)
{
  const int r = lane & 15, q = lane >> 4;
  f32x4 zv = {0.f, 0.f, 0.f, 0.f};
  f32x4 acc[2][NTW];
#pragma unroll
  for (int a = 0; a < 2; ++a)
#pragma unroll
    for (int b = 0; b < NTW; ++b) acc[a][b] = zv;

#pragma unroll
  for (int kk = 0; kk < KP/32; ++kk) {
    bf16x8 afrag[2];
#pragma unroll
    for (int rb = 0; rb < 2; ++rb) {
      int row = rb*16 + r;
      int byte = (row*KP + kk*32 + q*8) * 2; byte ^= ((row & 7) << 4);
      afrag[rb] = *reinterpret_cast<const bf16x8*>((const char*)inb + byte);
    }
#pragma unroll
    for (int nt = 0; nt < NTW; ++nt) {
      bf16x8 bfrag = *reinterpret_cast<const bf16x8*>(Bp + ((size_t)(kk*NTtot + ntbase + nt)*64 + lane)*8);
#pragma unroll
      for (int rb = 0; rb < 2; ++rb)
        acc[rb][nt] = __builtin_amdgcn_mfma_f32_16x16x32_bf16(afrag[rb], bfrag, acc[rb][nt], 0, 0, 0);
    }
  }
#pragma unroll
  for (int nt = 0; nt < NTW; ++nt) {
    int col = (ntbase + nt)*16 + r;
    float bias = bp[col];
#pragma unroll
    for (int rb = 0; rb < 2; ++rb)
#pragma unroll
      for (int i = 0; i < 4; ++i) {
        int row = rb*16 + q*4 + i;
        float v = swishf(acc[rb][nt][i] + bias);
        int byte = row*outPitchB + col*2; byte ^= ((row & 7) << 4);
        *(uint16_t*)((char*)outb + byte) = f2bf(v);
      }
  }
}

// ---------------- edge megakernel (32 edges / block, 8 waves) ----------------
template<int LAYER>
__global__ __launch_bounds__(512, 4)
void edge_kernel(const float* __restrict__ pos, const int* __restrict__ eidx,
                 const char* __restrict__ ws, float* __restrict__ aggout,
                 const float* __restrict__ hsrc)
{
  __shared__ __align__(16) uint16_t actA[MT*512];
  __shared__ __align__(16) uint16_t actB[MT*512];
  __shared__ float mbuf[MT*50];   // L1: m0(40)+m1raw(10)/edge. L2: [0..31]=medge, [32..351]=D
  __shared__ float xjb[MT*60];    // L1: pitch 30. L2: pitch 60
  __shared__ float shl[MT*3];     // sqrt(3)*unit/sqrt(20)
  __shared__ float rbuf[MT];
  __shared__ int   rowl[MT];
  __shared__ int   coll[MT];

  const uint16_t* W1p = (const uint16_t*)(ws + (LAYER==1 ? OFF_W1P1 : OFF_W1P2));
  const uint16_t* W2p = (const uint16_t*)(ws + (LAYER==1 ? OFF_W2P1 : OFF_W2P2));
  const uint16_t* W3p = (const uint16_t*)(ws + (LAYER==1 ? OFF_W3P1 : OFF_W3P2));
  const uint16_t* W4p = (const uint16_t*)(ws + (LAYER==1 ? OFF_W4P1 : OFF_W4P2));
  const float* b1p = (const float*)(ws + (LAYER==1 ? OFF_B1P1 : OFF_B1P2));
  const float* b2p = (const float*)(ws + (LAYER==1 ? OFF_B2P1 : OFF_B2P2));
  const float* b3p = (const float*)(ws + (LAYER==1 ? OFF_B3P1 : OFF_B3P2));
  const float* b4p = (const float*)(ws + (LAYER==1 ? OFF_B4P1 : OFF_B4P2));

  const int tid  = threadIdx.x;
  const int lane = tid & 63;
  const int wv   = tid >> 6;
  const int e0   = blockIdx.x * MT;

  // stage 0: edge meta
  if (tid < MT) {
    int e = e0 + tid;
    int rn = eidx[e];
    int cn = eidx[E_EDGES + e];
    rowl[tid] = rn; coll[tid] = cn;
    float ax = pos[rn*3+0] - pos[cn*3+0];
    float ay = pos[rn*3+1] - pos[cn*3+1];
    float az = pos[rn*3+2] - pos[cn*3+2];
    float rr = sqrtf(ax*ax + ay*ay + az*az + 1e-12f);
    rbuf[tid] = rr;
    float s = SQRT3C * SH0C / rr;
    shl[tid*3+0] = ax*s; shl[tid*3+1] = ay*s; shl[tid*3+2] = az*s;
  }
  __syncthreads();

  // stage 0b: basis into actB (pitch 64 elems), xj gather, zero message buffers
  for (int i = tid; i < MT*64; i += 512) {
    int e = i >> 6, c = i & 63;
    float v = 0.f;
    if (c < 40) { float t = rbuf[e]*3.9f - (float)c; v = __expf(-t*t); }
    int byte = (e*64 + c)*2; byte ^= ((e & 7) << 4);
    *(uint16_t*)((char*)actB + byte) = f2bf(v);
  }
  if (LAYER == 1) {
    for (int i = tid; i < MT*30; i += 512) {
      int e = i/30, u = i - e*30;
      xjb[i] = hsrc[(size_t)rowl[e]*32 + u];
    }
    for (int i = tid; i < MT*50; i += 512) mbuf[i] = 0.f;
  } else {
    for (int i = tid; i < MT*60; i += 512) {
      int e = i/60, u = i - e*60;
      xjb[i] = hsrc[(size_t)rowl[e]*64 + u];
    }
    if (tid < MT) mbuf[tid] = 0.f;
  }
  __syncthreads();

  if (LAYER == 2) {
    // D[e][v] = sum_m xj2[e,30+v*3+m]*sh[m]/sqrt(3)  -> mbuf[MT + e*10 + v]
    for (int i = tid; i < MT*10; i += 512) {
      int e = i/10, v = i - e*10;
      float d = 0.f;
#pragma unroll
      for (int m = 0; m < 3; ++m) d += xjb[e*60 + 30 + v*3 + m] * shl[e*3 + m];
      mbuf[MT + i] = d * INV_SQRT3;
    }
  }

  // GEMM1: basis(actB, pitch 64) -> act1(actA, pitch 512), swish
  gemm_stage<64, 4>(actB, actA, W1p, b1p, 32, wv*4, lane, 1024);
  __syncthreads();
  // GEMM2: act1(actA) -> act2(actB), swish
  gemm_stage<512, 4>(actA, actB, W2p, b2p, 32, wv*4, lane, 1024);
  __syncthreads();

  // GEMM3: act2(actB, pitch 512) -> x3(actA, pitch 64), swish — 8 waves: (rb,nt)=(wv>>2, wv&3)
  {
    const int r = lane & 15, q = lane >> 4;
    const int rb3 = wv >> 2, nt3 = wv & 3;
    f32x4 acc = {0.f, 0.f, 0.f, 0.f};
#pragma unroll
    for (int kk = 0; kk < 16; ++kk) {
      int row = rb3*16 + r;
      int byte = (row*512 + kk*32 + q*8) * 2; byte ^= ((row & 7) << 4);
      bf16x8 afrag = *reinterpret_cast<const bf16x8*>((const char*)actB + byte);
      bf16x8 bfrag = *reinterpret_cast<const bf16x8*>(W3p + ((size_t)(kk*4 + nt3)*64 + lane)*8);
      acc = __builtin_amdgcn_mfma_f32_16x16x32_bf16(afrag, bfrag, acc, 0, 0, 0);
    }
    int col = nt3*16 + r;
    float bias = b3p[col];
#pragma unroll
    for (int i = 0; i < 4; ++i) {
      int row = rb3*16 + q*4 + i;
      float v = swishf(acc[i] + bias);
      int byte = row*128 + col*2; byte ^= ((row & 7) << 4);
      *(uint16_t*)((char*)actA + byte) = f2bf(v);
    }
  }
  __syncthreads();

  // GEMM4 + in-register consumption
  const int r_ = lane & 15, q_ = lane >> 4;
  f32x4 zv = {0.f, 0.f, 0.f, 0.f};
  if (LAYER == 1) {
#pragma unroll
    for (int ch = 0; ch < 3; ++ch) {
      f32x4 acc[2][4];
#pragma unroll
      for (int a = 0; a < 2; ++a)
#pragma unroll
        for (int b = 0; b < 4; ++b) acc[a][b] = zv;
#pragma unroll
      for (int kk = 0; kk < 2; ++kk) {
        bf16x8 afrag[2];
#pragma unroll
        for (int rb = 0; rb < 2; ++rb) {
          int row = rb*16 + r_;
          int byte = (row*64 + kk*32 + q_*8)*2; byte ^= ((row & 7) << 4);
          afrag[rb] = *reinterpret_cast<const bf16x8*>((const char*)actA + byte);
        }
#pragma unroll
        for (int nt = 0; nt < 4; ++nt) {
          int ntg = wv*12 + ch*4 + nt;
          bf16x8 bfrag = *reinterpret_cast<const bf16x8*>(W4p + ((size_t)(kk*96 + ntg)*64 + lane)*8);
#pragma unroll
          for (int rb = 0; rb < 2; ++rb)
            acc[rb][nt] = __builtin_amdgcn_mfma_f32_16x16x32_bf16(afrag[rb], bfrag, acc[rb][nt], 0, 0, 0);
        }
      }
#pragma unroll
      for (int nt = 0; nt < 4; ++nt) {
        int cg = (wv*12 + ch*4 + nt)*16 + r_;
        if (cg < 1500) {
          float bias = b4p[cg];
          int u, vd;
          if (cg < 1200) { u = cg/40; vd = cg - u*40; }
          else { int cc = cg - 1200; u = cc/10; vd = 40 + (cc - u*10); }
#pragma unroll
          for (int rb = 0; rb < 2; ++rb)
#pragma unroll
            for (int i2 = 0; i2 < 4; ++i2) {
              int e = rb*16 + q_*4 + i2;
              float w = acc[rb][nt][i2] + bias;
              atomicAdd(&mbuf[e*50 + vd], xjb[e*30 + u] * w);
            }
        }
      }
    }
  } else {
    // N=64 (40 real): 8 waves, (rb,nt) = (wv>>2, wv&3)
    const int rb4 = wv >> 2, nt4 = wv & 3;
    f32x4 acc = zv;
#pragma unroll
    for (int kk = 0; kk < 2; ++kk) {
      int row = rb4*16 + r_;
      int byte = (row*64 + kk*32 + q_*8)*2; byte ^= ((row & 7) << 4);
      bf16x8 afrag = *reinterpret_cast<const bf16x8*>((const char*)actA + byte);
      bf16x8 bfrag = *reinterpret_cast<const bf16x8*>(W4p + ((size_t)(kk*4 + nt4)*64 + lane)*8);
      acc = __builtin_amdgcn_mfma_f32_16x16x32_bf16(afrag, bfrag, acc, 0, 0, 0);
    }
    int cg = nt4*16 + r_;
    if (cg < 40) {
      float bias = b4p[cg];
#pragma unroll
      for (int i2 = 0; i2 < 4; ++i2) {
        int e = rb4*16 + q_*4 + i2;
        float w = acc[i2] + bias;
        float contrib = (cg < 30) ? xjb[e*60 + cg] * w * (SH0C * INV_SQRT30)
                                  : mbuf[MT + e*10 + (cg - 30)] * w * INV_SQRT10;
        atomicAdd(&mbuf[e], contrib);
      }
    }
  }
  __syncthreads();

  // scatter to aggregation buffers
  if (LAYER == 1) {
    for (int i = tid; i < MT*70; i += 512) {
      int e = i/70, c = i - e*70;
      float v;
      if (c < 40) v = mbuf[e*50 + c] * SH0C;
      else { int vv = (c - 40)/3, k = (c - 40) - vv*3; v = mbuf[e*50 + 40 + vv] * shl[e*3 + k]; }
      atomicAdd(&aggout[(size_t)coll[e]*70 + c], v);
    }
  } else {
    if (tid < MT) atomicAdd(&aggout[coll[tid]], mbuf[tid]);
  }
}

// ---------------- node kernels ----------------
__global__ void node_mid(char* ws, const float* __restrict__ si1w)
{
  int nid = blockIdx.x * blockDim.x + threadIdx.x;
  if (nid >= N_NODES) return;
  const float* hN  = (const float*)(ws + OFF_HN)  + (size_t)nid*32;
  const float* agg = (const float*)(ws + OFF_AGG) + (size_t)nid*70;
  float* h2        = (float*)(ws + OFF_H2)        + (size_t)nid*64;

  float hn[30];
#pragma unroll
  for (int u = 0; u < 30; ++u) hn[u] = hN[u];   // already /sqrt(30)

  float h1[70];
#pragma unroll
  for (int v = 0; v < 40; ++v) {
    float s = 0.f;
#pragma unroll
    for (int u = 0; u < 30; ++u) s += hn[u] * si1w[u*40 + v];
    h1[v] = SQ2C * (s + agg[v]);
  }
#pragma unroll
  for (int c = 40; c < 70; ++c) h1[c] = agg[c];

#pragma unroll
  for (int u = 0; u < 30; ++u) h2[u] = swishf(h1[u]);
#pragma unroll
  for (int v = 0; v < 10; ++v) {
    float g = 1.f / (1.f + __expf(-h1[30 + v]));
#pragma unroll
    for (int k = 0; k < 3; ++k) h2[30 + v*3 + k] = h1[40 + v*3 + k] * g;
  }
}

__global__ void node_final(char* ws, const float* __restrict__ si2w, const int* __restrict__ batch)
{
  __shared__ float ls[NGRAPH];
  if (threadIdx.x < NGRAPH) ls[threadIdx.x] = 0.f;
  __syncthreads();
  int nid = blockIdx.x * blockDim.x + threadIdx.x;
  if (nid < N_NODES) {
    const float* h2   = (const float*)(ws + OFF_H2) + (size_t)nid*64;
    const float* agg2 = (const float*)(ws + OFF_AGG2);
    float s2 = 0.f;
#pragma unroll
    for (int u = 0; u < 30; ++u) s2 += h2[u] * si2w[u];
    float val = SQ2C * (s2 * INV_SQRT30 + agg2[nid]);
    atomicAdd(&ls[batch[nid]], val);
  }
  __syncthreads();
  if (threadIdx.x < NGRAPH)
    atomicAdd(((float*)(ws + OFF_GSUM)) + threadIdx.x, ls[threadIdx.x]);
}

__global__ void write_out(const char* ws, float* out)
{
  int g = threadIdx.x;
  if (g < NGRAPH) out[g] = ((const float*)(ws + OFF_GSUM))[g];
}

// ---------------- launch ----------------
extern "C" void kernel_launch(void* const* d_in, const int* in_sizes, int n_in,
                              void* d_out, int out_size, void* d_ws, size_t ws_size,
                              hipStream_t stream)
{
  const float* pos  = (const float*)d_in[0];
  const float* emb  = (const float*)d_in[1];
  const float* si1w = (const float*)d_in[2];
  const float* si2w = (const float*)d_in[3];
  const float* w1a = (const float*)d_in[4];  const float* b1a = (const float*)d_in[5];
  const float* w2a = (const float*)d_in[6];  const float* b2a = (const float*)d_in[7];
  const float* w3a = (const float*)d_in[8];  const float* b3a = (const float*)d_in[9];
  const float* w4a = (const float*)d_in[10]; const float* b4a = (const float*)d_in[11];
  const float* w1b = (const float*)d_in[12]; const float* b1b = (const float*)d_in[13];
  const float* w2b = (const float*)d_in[14]; const float* b2b = (const float*)d_in[15];
  const float* w3b = (const float*)d_in[16]; const float* b3b = (const float*)d_in[17];
  const float* w4b = (const float*)d_in[18]; const float* b4b = (const float*)d_in[19];
  const int* z     = (const int*)d_in[20];
  const int* eidx  = (const int*)d_in[21];
  const int* batch = (const int*)d_in[22];
  char* ws = (char*)d_ws;

  // zero accumulation buffers (agg, agg2, gsum are contiguous)
  hipMemsetAsync(ws + OFF_AGG, 0, OFF_END - OFF_AGG, stream);

  prep_kernel<<<1409, 256, 0, stream>>>(w1a, w2a, w3a, w4a, w1b, w2b, w3b, w4b,
                                        b1a, b2a, b3a, b4a, b1b, b2b, b3b, b4b,
                                        emb, z, ws);

  edge_kernel<1><<<E_EDGES/MT, 512, 0, stream>>>(pos, eidx, ws,
                                                 (float*)(ws + OFF_AGG),
                                                 (const float*)(ws + OFF_HN));

  node_mid<<<N_NODES/256, 256, 0, stream>>>(ws, si1w);

  edge_kernel<2><<<E_EDGES/MT, 512, 0, stream>>>(pos, eidx, ws,
                                                 (float*)(ws + OFF_AGG2),
                                                 (const float*)(ws + OFF_H2));

  node_final<<<N_NODES/256, 256, 0, stream>>>(ws, si2w, batch);

  write_out<<<1, 64, 0, stream>>>(ws, (float*)d_out);
}

// Round 5
// 1728.793 us; speedup vs baseline: 1.1668x; 1.0043x over previous
//
#include <hip/hip_runtime.h>
#include <stdint.h>

typedef __attribute__((ext_vector_type(8))) short bf16x8;
typedef __attribute__((ext_vector_type(4))) float f32x4;

#define N_NODES 8192
#define E_EDGES 163840
#define NGRAPH  32
#define MT      32          /* edges per block */

#define INV_SQRT30 0.18257419f
#define SH0C       0.22360680f   /* 1/sqrt(20) */
#define SQRT3C     1.73205081f
#define INV_SQRT3  0.57735027f
#define INV_SQRT10 0.31622777f
#define SQ2C       0.70710678f

// ---------------- workspace layout (bytes) ----------------
enum : unsigned {
  OFF_W1P1 = 0u,       OFF_W2P1 = 65536u,   OFF_W3P1 = 589824u,  OFF_W4P1 = 655360u,
  OFF_W1P2 = 851968u,  OFF_W2P2 = 917504u,  OFF_W3P2 = 1441792u, OFF_W4P2 = 1507328u,
  OFF_B1P1 = 1515520u, OFF_B2P1 = 1517568u, OFF_B3P1 = 1519616u, OFF_B4P1 = 1519872u,
  OFF_B1P2 = 1526016u, OFF_B2P2 = 1528064u, OFF_B3P2 = 1530112u, OFF_B4P2 = 1530368u,
  OFF_HN   = 1530624u, // [8192][32] f32  (emb[z]/sqrt(30))
  OFF_H2   = 2579200u, // [8192][64] f32
  OFF_AGG  = 4676352u, // [8192][70] f32
  OFF_AGG2 = 6970112u, // [8192] f32
  OFF_GSUM = 7002880u, // [32] f32
  OFF_END  = 7003008u
};

__device__ __forceinline__ uint16_t f2bf(float f){
  union { float f; uint32_t u; } v; v.f = f;
  uint32_t r = v.u + 0x7fffu + ((v.u >> 16) & 1u);
  return (uint16_t)(r >> 16);
}
__device__ __forceinline__ float swishf(float x){ return x / (1.f + __expf(-x)); }

// ---------------- weight pre-pack (f32 src -> bf16 MFMA B-fragment order) ----------------
__device__ __forceinline__ void pack_mat(const float* __restrict__ src, int K, int N, int NP,
                                         uint16_t* __restrict__ dst, int t)
{
  int lane = t & 63;
  int tile = t >> 6;
  int NT = NP >> 4;
  int nn = tile % NT, kk = tile / NT;
  int k0 = kk*32 + ((lane >> 4) << 3);
  int n  = nn*16 + (lane & 15);
  union { short s[8]; bf16x8 v; } tmp;
#pragma unroll
  for (int b = 0; b < 8; ++b) {
    int k = k0 + b;
    tmp.s[b] = (k < K && n < N) ? (short)f2bf(src[(size_t)k*N + n]) : (short)0;
  }
  *reinterpret_cast<bf16x8*>(dst + (size_t)t*8) = tmp.v;
}

__global__ void prep_kernel(const float* w1a, const float* w2a, const float* w3a, const float* w4a,
                            const float* w1b, const float* w2b, const float* w3b, const float* w4b,
                            const float* b1a, const float* b2a, const float* b3a, const float* b4a,
                            const float* b1b, const float* b2b, const float* b3b, const float* b4b,
                            const float* emb, const int* z, char* ws)
{
  int t = blockIdx.x * 256 + threadIdx.x;
  if      (t < 4096)   pack_mat(w1a, 40, 500, 512,  (uint16_t*)(ws + OFF_W1P1), t);
  else if (t < 36864)  pack_mat(w2a, 500,500, 512,  (uint16_t*)(ws + OFF_W2P1), t - 4096);
  else if (t < 40960)  pack_mat(w3a, 500, 50, 64,   (uint16_t*)(ws + OFF_W3P1), t - 36864);
  else if (t < 53248)  pack_mat(w4a, 50,1500, 1536, (uint16_t*)(ws + OFF_W4P1), t - 40960);
  else if (t < 57344)  pack_mat(w1b, 40, 500, 512,  (uint16_t*)(ws + OFF_W1P2), t - 53248);
  else if (t < 90112)  pack_mat(w2b, 500,500, 512,  (uint16_t*)(ws + OFF_W2P2), t - 57344);
  else if (t < 94208)  pack_mat(w3b, 500, 50, 64,   (uint16_t*)(ws + OFF_W3P2), t - 90112);
  else if (t < 94720)  pack_mat(w4b, 50,  40, 64,   (uint16_t*)(ws + OFF_W4P2), t - 94208);
  else if (t < 98496) {
    int loc = t - 94720;
    const float* src; float* dst; int realN;
    if      (loc < 512)  { src=b1a; dst=(float*)(ws+OFF_B1P1); realN=500; }
    else if (loc < 1024) { src=b2a; dst=(float*)(ws+OFF_B2P1); realN=500;  loc -= 512;  }
    else if (loc < 1088) { src=b3a; dst=(float*)(ws+OFF_B3P1); realN=50;   loc -= 1024; }
    else if (loc < 2624) { src=b4a; dst=(float*)(ws+OFF_B4P1); realN=1500; loc -= 1088; }
    else if (loc < 3136) { src=b1b; dst=(float*)(ws+OFF_B1P2); realN=500;  loc -= 2624; }
    else if (loc < 3648) { src=b2b; dst=(float*)(ws+OFF_B2P2); realN=500;  loc -= 3136; }
    else if (loc < 3712) { src=b3b; dst=(float*)(ws+OFF_B3P2); realN=50;   loc -= 3648; }
    else                 { src=b4b; dst=(float*)(ws+OFF_B4P2); realN=40;   loc -= 3712; }
    dst[loc] = (loc < realN) ? src[loc] : 0.f;
  }
  else if (t < 360640) {
    int i = t - 98496;
    int n = i >> 5, u = i & 31;
    float v = 0.f;
    if (u < 30) v = emb[(size_t)z[n]*30 + u] * INV_SQRT30;
    ((float*)(ws + OFF_HN))[i] = v;
  }
}

// ---------------- pipelined GEMM stage (1-deep prefetch of A(LDS) + B(global)) ----------------
template<int KP, int NTW>
__device__ __forceinline__ void gemm_stage(const uint16_t* inb, uint16_t* outb,
                                           const uint16_t* __restrict__ Bp, const float* __restrict__ bp,
                                           int NTtot, int ntbase, int lane, int outPitchB)
{
  const int r = lane & 15, q = lane >> 4;
  constexpr int NK = KP/32;
  const bf16x8* __restrict__ bv = reinterpret_cast<const bf16x8*>(Bp);
  const int bbase = ntbase*64 + lane;
  const int bstep = NTtot*64;
  const char* inbc = (const char*)inb;

  f32x4 zv = {0.f, 0.f, 0.f, 0.f};
  f32x4 acc[2][NTW];
#pragma unroll
  for (int a = 0; a < 2; ++a)
#pragma unroll
    for (int b = 0; b < NTW; ++b) acc[a][b] = zv;

  bf16x8 abuf[2][2], bbuf[2][NTW];
#pragma unroll
  for (int rb = 0; rb < 2; ++rb) {
    int row = rb*16 + r;
    int byte = (row*KP + q*8)*2; byte ^= ((row & 7) << 4);
    abuf[0][rb] = *reinterpret_cast<const bf16x8*>(inbc + byte);
  }
#pragma unroll
  for (int nt = 0; nt < NTW; ++nt) bbuf[0][nt] = bv[bbase + nt*64];

#pragma unroll
  for (int kk = 0; kk < NK; ++kk) {
    const int cur = kk & 1, nxt = cur ^ 1;
    if (kk + 1 < NK) {
#pragma unroll
      for (int rb = 0; rb < 2; ++rb) {
        int row = rb*16 + r;
        int byte = (row*KP + (kk+1)*32 + q*8)*2; byte ^= ((row & 7) << 4);
        abuf[nxt][rb] = *reinterpret_cast<const bf16x8*>(inbc + byte);
      }
#pragma unroll
      for (int nt = 0; nt < NTW; ++nt) bbuf[nxt][nt] = bv[bbase + (kk+1)*bstep + nt*64];
    }
#pragma unroll
    for (int nt = 0; nt < NTW; ++nt)
#pragma unroll
      for (int rb = 0; rb < 2; ++rb)
        acc[rb][nt] = __builtin_amdgcn_mfma_f32_16x16x32_bf16(abuf[cur][rb], bbuf[cur][nt], acc[rb][nt], 0, 0, 0);
  }

#pragma unroll
  for (int nt = 0; nt < NTW; ++nt) {
    int col = (ntbase + nt)*16 + r;
    float bias = bp[col];
#pragma unroll
    for (int rb = 0; rb < 2; ++rb)
#pragma unroll
      for (int i = 0; i < 4; ++i) {
        int row = rb*16 + q*4 + i;
        float v = swishf(acc[rb][nt][i] + bias);
        int byte = row*outPitchB + col*2; byte ^= ((row & 7) << 4);
        *(uint16_t*)((char*)outb + byte) = f2bf(v);
      }
  }
}

// ---------------- edge megakernel (32 edges / block, 8 waves) ----------------
template<int LAYER>
__global__ __launch_bounds__(512, 4)
void edge_kernel(const float* __restrict__ pos, const int* __restrict__ eidx,
                 const char* __restrict__ ws, float* __restrict__ aggout,
                 const float* __restrict__ hsrc)
{
  __shared__ __align__(16) uint16_t actA[MT*512];
  __shared__ __align__(16) uint16_t actB[MT*512];
  __shared__ float mbuf[MT*50];
  __shared__ float xjb[MT*60];
  __shared__ float shl[MT*3];
  __shared__ float rbuf[MT];
  __shared__ int   rowl[MT];
  __shared__ int   coll[MT];

  const uint16_t* W1p = (const uint16_t*)(ws + (LAYER==1 ? OFF_W1P1 : OFF_W1P2));
  const uint16_t* W2p = (const uint16_t*)(ws + (LAYER==1 ? OFF_W2P1 : OFF_W2P2));
  const uint16_t* W3p = (const uint16_t*)(ws + (LAYER==1 ? OFF_W3P1 : OFF_W3P2));
  const uint16_t* W4p = (const uint16_t*)(ws + (LAYER==1 ? OFF_W4P1 : OFF_W4P2));
  const float* b1p = (const float*)(ws + (LAYER==1 ? OFF_B1P1 : OFF_B1P2));
  const float* b2p = (const float*)(ws + (LAYER==1 ? OFF_B2P1 : OFF_B2P2));
  const float* b3p = (const float*)(ws + (LAYER==1 ? OFF_B3P1 : OFF_B3P2));
  const float* b4p = (const float*)(ws + (LAYER==1 ? OFF_B4P1 : OFF_B4P2));

  const int tid  = threadIdx.x;
  const int lane = tid & 63;
  const int wv   = tid >> 6;
  const int e0   = blockIdx.x * MT;

  // stage 0: edge meta
  if (tid < MT) {
    int e = e0 + tid;
    int rn = eidx[e];
    int cn = eidx[E_EDGES + e];
    rowl[tid] = rn; coll[tid] = cn;
    float ax = pos[rn*3+0] - pos[cn*3+0];
    float ay = pos[rn*3+1] - pos[cn*3+1];
    float az = pos[rn*3+2] - pos[cn*3+2];
    float rr = sqrtf(ax*ax + ay*ay + az*az + 1e-12f);
    rbuf[tid] = rr;
    float s = SQRT3C * SH0C / rr;
    shl[tid*3+0] = ax*s; shl[tid*3+1] = ay*s; shl[tid*3+2] = az*s;
  }
  __syncthreads();

  // stage 0b: basis into actB (pitch 64 elems), xj gather, zero message buffers
  for (int i = tid; i < MT*64; i += 512) {
    int e = i >> 6, c = i & 63;
    float v = 0.f;
    if (c < 40) { float t = rbuf[e]*3.9f - (float)c; v = __expf(-t*t); }
    int byte = (e*64 + c)*2; byte ^= ((e & 7) << 4);
    *(uint16_t*)((char*)actB + byte) = f2bf(v);
  }
  if (LAYER == 1) {
    for (int i = tid; i < MT*30; i += 512) {
      int e = i/30, u = i - e*30;
      xjb[i] = hsrc[(size_t)rowl[e]*32 + u];
    }
    for (int i = tid; i < MT*50; i += 512) mbuf[i] = 0.f;
  } else {
    for (int i = tid; i < MT*60; i += 512) {
      int e = i/60, u = i - e*60;
      xjb[i] = hsrc[(size_t)rowl[e]*64 + u];
    }
    if (tid < MT) mbuf[tid] = 0.f;
  }
  __syncthreads();

  if (LAYER == 2) {
    for (int i = tid; i < MT*10; i += 512) {
      int e = i/10, v = i - e*10;
      float d = 0.f;
#pragma unroll
      for (int m = 0; m < 3; ++m) d += xjb[e*60 + 30 + v*3 + m] * shl[e*3 + m];
      mbuf[MT + i] = d * INV_SQRT3;
    }
  }

  // GEMM1: basis(actB, pitch 64) -> act1(actA, pitch 512), swish
  gemm_stage<64, 4>(actB, actA, W1p, b1p, 32, wv*4, lane, 1024);
  __syncthreads();
  // GEMM2: act1(actA) -> act2(actB), swish
  gemm_stage<512, 4>(actA, actB, W2p, b2p, 32, wv*4, lane, 1024);
  __syncthreads();

  // GEMM3: act2(actB, pitch 512) -> x3(actA, pitch 64), swish — 8 waves: (rb,nt)=(wv>>2, wv&3)
  {
    const int r = lane & 15, q = lane >> 4;
    const int rb3 = wv >> 2, nt3 = wv & 3;
    const bf16x8* __restrict__ bv = reinterpret_cast<const bf16x8*>(W3p);
    f32x4 acc = {0.f, 0.f, 0.f, 0.f};
    bf16x8 ab[2], bb[2];
    {
      int row = rb3*16 + r;
      int byte = (row*512 + q*8)*2; byte ^= ((row & 7) << 4);
      ab[0] = *reinterpret_cast<const bf16x8*>((const char*)actB + byte);
      bb[0] = bv[nt3*64 + lane];
    }
#pragma unroll
    for (int kk = 0; kk < 16; ++kk) {
      const int cur = kk & 1, nxt = cur ^ 1;
      if (kk + 1 < 16) {
        int row = rb3*16 + r;
        int byte = (row*512 + (kk+1)*32 + q*8)*2; byte ^= ((row & 7) << 4);
        ab[nxt] = *reinterpret_cast<const bf16x8*>((const char*)actB + byte);
        bb[nxt] = bv[((kk+1)*4 + nt3)*64 + lane];
      }
      acc = __builtin_amdgcn_mfma_f32_16x16x32_bf16(ab[cur], bb[cur], acc, 0, 0, 0);
    }
    int col = nt3*16 + r;
    float bias = b3p[col];
#pragma unroll
    for (int i = 0; i < 4; ++i) {
      int row = rb3*16 + q*4 + i;
      float v = swishf(acc[i] + bias);
      int byte = row*128 + col*2; byte ^= ((row & 7) << 4);
      *(uint16_t*)((char*)actA + byte) = f2bf(v);
    }
  }
  __syncthreads();

  // GEMM4 + in-register consumption
  const int r_ = lane & 15, q_ = lane >> 4;
  f32x4 zv = {0.f, 0.f, 0.f, 0.f};
  if (LAYER == 1) {
    // hoist A fragments (ch-invariant): [kk][rb]
    bf16x8 a4[2][2];
#pragma unroll
    for (int kk = 0; kk < 2; ++kk)
#pragma unroll
      for (int rb = 0; rb < 2; ++rb) {
        int row = rb*16 + r_;
        int byte = (row*64 + kk*32 + q_*8)*2; byte ^= ((row & 7) << 4);
        a4[kk][rb] = *reinterpret_cast<const bf16x8*>((const char*)actA + byte);
      }
    const bf16x8* __restrict__ bv4 = reinterpret_cast<const bf16x8*>(W4p);
#pragma unroll
    for (int ch = 0; ch < 3; ++ch) {
      // preload the 8 B fragments of this chunk
      bf16x8 b4[2][4];
#pragma unroll
      for (int kk = 0; kk < 2; ++kk)
#pragma unroll
        for (int nt = 0; nt < 4; ++nt)
          b4[kk][nt] = bv4[(kk*96 + wv*12 + ch*4 + nt)*64 + lane];
      f32x4 acc[2][4];
#pragma unroll
      for (int a = 0; a < 2; ++a)
#pragma unroll
        for (int b = 0; b < 4; ++b) acc[a][b] = zv;
#pragma unroll
      for (int kk = 0; kk < 2; ++kk)
#pragma unroll
        for (int nt = 0; nt < 4; ++nt)
#pragma unroll
          for (int rb = 0; rb < 2; ++rb)
            acc[rb][nt] = __builtin_amdgcn_mfma_f32_16x16x32_bf16(a4[kk][rb], b4[kk][nt], acc[rb][nt], 0, 0, 0);
#pragma unroll
      for (int nt = 0; nt < 4; ++nt) {
        int cg = (wv*12 + ch*4 + nt)*16 + r_;
        if (cg < 1500) {
          float bias = b4p[cg];
          int u, vd;
          if (cg < 1200) { u = cg/40; vd = cg - u*40; }
          else { int cc = cg - 1200; u = cc/10; vd = 40 + (cc - u*10); }
#pragma unroll
          for (int rb = 0; rb < 2; ++rb)
#pragma unroll
            for (int i2 = 0; i2 < 4; ++i2) {
              int e = rb*16 + q_*4 + i2;
              float w = acc[rb][nt][i2] + bias;
              atomicAdd(&mbuf[e*50 + vd], xjb[e*30 + u] * w);
            }
        }
      }
    }
  } else {
    // N=64 (40 real): 8 waves, (rb,nt) = (wv>>2, wv&3)
    const int rb4 = wv >> 2, nt4 = wv & 3;
    const bf16x8* __restrict__ bv4 = reinterpret_cast<const bf16x8*>(W4p);
    bf16x8 a4[2], b4[2];
#pragma unroll
    for (int kk = 0; kk < 2; ++kk) {
      int row = rb4*16 + r_;
      int byte = (row*64 + kk*32 + q_*8)*2; byte ^= ((row & 7) << 4);
      a4[kk] = *reinterpret_cast<const bf16x8*>((const char*)actA + byte);
      b4[kk] = bv4[(kk*4 + nt4)*64 + lane];
    }
    f32x4 acc = zv;
#pragma unroll
    for (int kk = 0; kk < 2; ++kk)
      acc = __builtin_amdgcn_mfma_f32_16x16x32_bf16(a4[kk], b4[kk], acc, 0, 0, 0);
    int cg = nt4*16 + r_;
    if (cg < 40) {
      float bias = b4p[cg];
#pragma unroll
      for (int i2 = 0; i2 < 4; ++i2) {
        int e = rb4*16 + q_*4 + i2;
        float w = acc[i2] + bias;
        float contrib = (cg < 30) ? xjb[e*60 + cg] * w * (SH0C * INV_SQRT30)
                                  : mbuf[MT + e*10 + (cg - 30)] * w * INV_SQRT10;
        atomicAdd(&mbuf[e], contrib);
      }
    }
  }
  __syncthreads();

  // scatter to aggregation buffers
  if (LAYER == 1) {
    for (int i = tid; i < MT*70; i += 512) {
      int e = i/70, c = i - e*70;
      float v;
      if (c < 40) v = mbuf[e*50 + c] * SH0C;
      else { int vv = (c - 40)/3, k = (c - 40) - vv*3; v = mbuf[e*50 + 40 + vv] * shl[e*3 + k]; }
      atomicAdd(&aggout[(size_t)coll[e]*70 + c], v);
    }
  } else {
    if (tid < MT) atomicAdd(&aggout[coll[tid]], mbuf[tid]);
  }
}

// ---------------- node kernels ----------------
__global__ void node_mid(char* ws, const float* __restrict__ si1w)
{
  int nid = blockIdx.x * blockDim.x + threadIdx.x;
  if (nid >= N_NODES) return;
  const float* hN  = (const float*)(ws + OFF_HN)  + (size_t)nid*32;
  const float* agg = (const float*)(ws + OFF_AGG) + (size_t)nid*70;
  float* h2        = (float*)(ws + OFF_H2)        + (size_t)nid*64;

  float hn[30];
#pragma unroll
  for (int u = 0; u < 30; ++u) hn[u] = hN[u];

  float h1[70];
#pragma unroll
  for (int v = 0; v < 40; ++v) {
    float s = 0.f;
#pragma unroll
    for (int u = 0; u < 30; ++u) s += hn[u] * si1w[u*40 + v];
    h1[v] = SQ2C * (s + agg[v]);
  }
#pragma unroll
  for (int c = 40; c < 70; ++c) h1[c] = agg[c];

#pragma unroll
  for (int u = 0; u < 30; ++u) h2[u] = swishf(h1[u]);
#pragma unroll
  for (int v = 0; v < 10; ++v) {
    float g = 1.f / (1.f + __expf(-h1[30 + v]));
#pragma unroll
    for (int k = 0; k < 3; ++k) h2[30 + v*3 + k] = h1[40 + v*3 + k] * g;
  }
}

__global__ void node_final(char* ws, const float* __restrict__ si2w, const int* __restrict__ batch)
{
  __shared__ float ls[NGRAPH];
  if (threadIdx.x < NGRAPH) ls[threadIdx.x] = 0.f;
  __syncthreads();
  int nid = blockIdx.x * blockDim.x + threadIdx.x;
  if (nid < N_NODES) {
    const float* h2   = (const float*)(ws + OFF_H2) + (size_t)nid*64;
    const float* agg2 = (const float*)(ws + OFF_AGG2);
    float s2 = 0.f;
#pragma unroll
    for (int u = 0; u < 30; ++u) s2 += h2[u] * si2w[u];
    float val = SQ2C * (s2 * INV_SQRT30 + agg2[nid]);
    atomicAdd(&ls[batch[nid]], val);
  }
  __syncthreads();
  if (threadIdx.x < NGRAPH)
    atomicAdd(((float*)(ws + OFF_GSUM)) + threadIdx.x, ls[threadIdx.x]);
}

__global__ void write_out(const char* ws, float* out)
{
  int g = threadIdx.x;
  if (g < NGRAPH) out[g] = ((const float*)(ws + OFF_GSUM))[g];
}

// ---------------- launch ----------------
extern "C" void kernel_launch(void* const* d_in, const int* in_sizes, int n_in,
                              void* d_out, int out_size, void* d_ws, size_t ws_size,
                              hipStream_t stream)
{
  const float* pos  = (const float*)d_in[0];
  const float* emb  = (const float*)d_in[1];
  const float* si1w = (const float*)d_in[2];
  const float* si2w = (const float*)d_in[3];
  const float* w1a = (const float*)d_in[4];  const float* b1a = (const float*)d_in[5];
  const float* w2a = (const float*)d_in[6];  const float* b2a = (const float*)d_in[7];
  const float* w3a = (const float*)d_in[8];  const float* b3a = (const float*)d_in[9];
  const float* w4a = (const float*)d_in[10]; const float* b4a = (const float*)d_in[11];
  const float* w1b = (const float*)d_in[12]; const float* b1b = (const float*)d_in[13];
  const float* w2b = (const float*)d_in[14]; const float* b2b = (const float*)d_in[15];
  const float* w3b = (const float*)d_in[16]; const float* b3b = (const float*)d_in[17];
  const float* w4b = (const float*)d_in[18]; const float* b4b = (const float*)d_in[19];
  const int* z     = (const int*)d_in[20];
  const int* eidx  = (const int*)d_in[21];
  const int* batch = (const int*)d_in[22];
  char* ws = (char*)d_ws;

  hipMemsetAsync(ws + OFF_AGG, 0, OFF_END - OFF_AGG, stream);

  prep_kernel<<<1409, 256, 0, stream>>>(w1a, w2a, w3a, w4a, w1b, w2b, w3b, w4b,
                                        b1a, b2a, b3a, b4a, b1b, b2b, b3b, b4b,
                                        emb, z, ws);

  edge_kernel<1><<<E_EDGES/MT, 512, 0, stream>>>(pos, eidx, ws,
                                                 (float*)(ws + OFF_AGG),
                                                 (const float*)(ws + OFF_HN));

  node_mid<<<N_NODES/256, 256, 0, stream>>>(ws, si1w);

  edge_kernel<2><<<E_EDGES/MT, 512, 0, stream>>>(pos, eidx, ws,
                                                 (float*)(ws + OFF_AGG2),
                                                 (const float*)(ws + OFF_H2));

  node_final<<<N_NODES/256, 256, 0, stream>>>(ws, si2w, batch);

  write_out<<<1, 64, 0, stream>>>(ws, (float*)d_out);
}